// Round 10
// baseline (161.444 us; speedup 1.0000x reference)
//
#include <hip/hip_runtime.h>

#define DIM   64
#define KCB   1024
#define RPB   256
#define QCAP  192      // per-wave queue (16 rows/wave -> 12/row margin), u16 items
#define BCH   256      // codebook entries staged per chunk (32 KB bf16)
#define NCH   (KCB / BCH)

// dynamic LDS layout (float words):
//  xs     [16384]               swizzled x (word = row*64 + ((cj^(row&15))<<2))
//  Atab   [256]  @16384
//  Ttab   [256]  @16640         (reused as dtab for the loss tree)
//  csq_s  [1024] @16896
//  keytab [256 u64] @17920 (512 words)
//  qcnt   [16 int] @18432
//  ovfl   @18448
//  qbuf   u16[16][QCAP] @18449  (1536 words) -> ends 19985
//  bsh    @19988 (16B-aligned): TWO buffers of BCH entries x 32 words each,
//         granule-swizzled (granule j of entry c stored at slot j^(c&7))
#define BSH_OFS 19988
#define BUF_USH (BCH * 64)                  // ushorts per buffer (16384)
#define SMEM_WORDS (BSH_OFS + 2 * BCH * 32) // 36372 words = 145,488 B -> 1 block/CU
#define SMEM_BYTES (SMEM_WORDS * 4)

// ws layout (floats): ws[0] = loss acc; ws[256..1279] = csq[k];
//                     ws[2048..] = cb_hi bf16 [1024][64] (32768 float slots)
#define WS_NEED_BYTES ((2048 + 32768) * 4)

typedef __attribute__((ext_vector_type(8))) short short8;
typedef __attribute__((ext_vector_type(4))) float f32x4;

__device__ __forceinline__ unsigned short f2bf(float f) {
    union { float f; unsigned u; } v; v.f = f;
    unsigned u = v.u;
    return (unsigned short)((u + 0x7FFFu + ((u >> 16) & 1u)) >> 16);  // RNE
}

__global__ void vq_prep(const float* __restrict__ cb, float* __restrict__ ws, int do_bf) {
    int k = blockIdx.x * blockDim.x + threadIdx.x;
    if (k < KCB) {
        const float4* e4 = (const float4*)(cb + (k << 6));
        float4 xq[16];
        #pragma unroll
        for (int j = 0; j < 16; ++j) xq[j] = e4[j];
        {
            #pragma clang fp contract(off)
            float racc[8];
            racc[0]=xq[0].x*xq[0].x; racc[1]=xq[0].y*xq[0].y;
            racc[2]=xq[0].z*xq[0].z; racc[3]=xq[0].w*xq[0].w;
            racc[4]=xq[1].x*xq[1].x; racc[5]=xq[1].y*xq[1].y;
            racc[6]=xq[1].z*xq[1].z; racc[7]=xq[1].w*xq[1].w;
            #pragma unroll
            for (int t = 1; t < 8; ++t) {
                float4 a = xq[2*t], b = xq[2*t+1];
                racc[0]+=a.x*a.x; racc[1]+=a.y*a.y; racc[2]+=a.z*a.z; racc[3]+=a.w*a.w;
                racc[4]+=b.x*b.x; racc[5]+=b.y*b.y; racc[6]+=b.z*b.z; racc[7]+=b.w*b.w;
            }
            ws[256 + k] = ((racc[0] + racc[1]) + (racc[2] + racc[3]))
                        + ((racc[4] + racc[5]) + (racc[6] + racc[7]));
        }
        if (do_bf) {
            short8* dst = (short8*)((unsigned short*)(ws + 2048) + (k << 6));
            #pragma unroll
            for (int p = 0; p < 8; ++p) {
                float4 v = xq[2*p], u = xq[2*p+1];
                short8 s;
                s[0]=(short)f2bf(v.x); s[1]=(short)f2bf(v.y);
                s[2]=(short)f2bf(v.z); s[3]=(short)f2bf(v.w);
                s[4]=(short)f2bf(u.x); s[5]=(short)f2bf(u.y);
                s[6]=(short)f2bf(u.z); s[7]=(short)f2bf(u.w);
                dst[p] = s;
            }
        }
    }
    if (k == 0) ws[0] = 0.0f;
}

// Two-pass MFMA-filtered VQ — LDS-shared B, DOUBLE-BUFFERED staging:
//  - R9 paid 2 barriers + an exposed L2->LDS latency per 128-entry chunk
//    (16 chunk-iters). R10: 256-entry chunks, two bsh buffers, register
//    prefetch of chunk i+1 issued before chunk i's compute, ONE barrier/chunk.
//    Buffer safety: buf[cur^1] last read in iter i-1, protected by that iter's
//    trailing barrier; same barrier publishes iter i's write before iter i+1.
//  - per-nt fmax/flag processing: fmax exact under any association; atomicMin
//    merge order-independent -> thresholds/flags/outputs bit-identical to R9.
__global__ __launch_bounds__(1024, 1) void vq_mfma(
        const float* __restrict__ in,
        const float* __restrict__ cb,
        float* __restrict__ ws,
        float* __restrict__ codes_f,
        float* __restrict__ out)
{
    extern __shared__ float smem[];
    float* xs    = smem;
    float* Atab  = smem + 16384;
    float* Ttab  = smem + 16640;                       // reused as dtab
    float* csq_s = smem + 16896;
    unsigned long long* keytab = (unsigned long long*)(smem + 17920);
    int* qcnt  = (int*)(smem + 18432);                 // [16]
    int* ovflp = (int*)(smem + 18448);
    unsigned short* qbuf = (unsigned short*)(smem + 18449);  // [16][QCAP], 1536 words
    unsigned short* bsh  = (unsigned short*)(smem + BSH_OFS); // 2 x BUF_USH

    const int tid  = threadIdx.x;
    const int lane = tid & 63;
    const int w    = tid >> 6;                         // wave 0..15
    const int r    = lane & 15;
    const int g    = lane >> 4;
    const int wrow = w << 4;                           // 16 rows per wave
    const size_t rowBase = (size_t)blockIdx.x * RPB;
    const float* csq = ws + 256;
    const unsigned short* cbh = (const unsigned short*)(ws + 2048);
    float* loss_acc = ws;

    // ---- stage x once (swizzled), csq, init tabs ----
    {
        const float4* gx = (const float4*)(in + rowBase * DIM);
        #pragma unroll
        for (int i = 0; i < 4; ++i) {
            int idx = i * 1024 + tid;
            int row = idx >> 4, cj = idx & 15;
            float4 v = gx[idx];
            *(float4*)(xs + row * 64 + ((cj ^ (row & 15)) << 2)) = v;
        }
    }
    csq_s[tid] = csq[tid];                             // 1024 threads cover KCB
    if (tid < RPB) keytab[tid] = 0xFFFFFFFFFFFFFFFFull;
    if (tid < 16) qcnt[tid] = 0;
    if (tid == 0) *ovflp = 0;
    __syncthreads();

    // ---- per-row A (exact pairwise-8 order), S1, tau (row = tid; from LDS) ----
    if (tid < RPB) {
        const float* xr = xs + tid * 64;
        const int s = tid & 15;
        float A, S1;
        {
            #pragma clang fp contract(off)
            float racc[8], sacc[8];
            {
                float4 a = *(const float4*)(xr + ((0 ^ s) << 2));
                float4 b = *(const float4*)(xr + ((1 ^ s) << 2));
                racc[0]=a.x*a.x; racc[1]=a.y*a.y; racc[2]=a.z*a.z; racc[3]=a.w*a.w;
                racc[4]=b.x*b.x; racc[5]=b.y*b.y; racc[6]=b.z*b.z; racc[7]=b.w*b.w;
                sacc[0]=__builtin_fabsf(a.x); sacc[1]=__builtin_fabsf(a.y);
                sacc[2]=__builtin_fabsf(a.z); sacc[3]=__builtin_fabsf(a.w);
                sacc[4]=__builtin_fabsf(b.x); sacc[5]=__builtin_fabsf(b.y);
                sacc[6]=__builtin_fabsf(b.z); sacc[7]=__builtin_fabsf(b.w);
            }
            #pragma unroll
            for (int t = 1; t < 8; ++t) {
                float4 a = *(const float4*)(xr + (((2*t)   ^ s) << 2));
                float4 b = *(const float4*)(xr + (((2*t+1) ^ s) << 2));
                racc[0]+=a.x*a.x; racc[1]+=a.y*a.y; racc[2]+=a.z*a.z; racc[3]+=a.w*a.w;
                racc[4]+=b.x*b.x; racc[5]+=b.y*b.y; racc[6]+=b.z*b.z; racc[7]+=b.w*b.w;
                sacc[0]+=__builtin_fabsf(a.x); sacc[1]+=__builtin_fabsf(a.y);
                sacc[2]+=__builtin_fabsf(a.z); sacc[3]+=__builtin_fabsf(a.w);
                sacc[4]+=__builtin_fabsf(b.x); sacc[5]+=__builtin_fabsf(b.y);
                sacc[6]+=__builtin_fabsf(b.z); sacc[7]+=__builtin_fabsf(b.w);
            }
            A  = ((racc[0]+racc[1])+(racc[2]+racc[3]))
               + ((racc[4]+racc[5])+(racc[6]+racc[7]));
            S1 = ((sacc[0]+sacc[1])+(sacc[2]+sacc[3]))
               + ((sacc[4]+sacc[5])+(sacc[6]+sacc[7]));
        }
        Atab[tid] = A;
        Ttab[tid] = 1.52587890625e-05f * S1
                  + 4.76837158203125e-07f * (A + 1.0f)
                  + 1e-5f;                             // certified >= 2E (R2-R9 verified)
    }

    // ---- A-fragments (bf16 hi of x) from LDS (row = wrow + r) ----
    short8 af[2];
    #pragma unroll
    for (int h = 0; h < 2; ++h) {
        const int row = wrow + r;                      // row&15 == r
        const int cj = h*8 + g*2;
        float4 v0 = *(const float4*)(xs + row*64 + (((cj  ) ^ r) << 2));
        float4 v1 = *(const float4*)(xs + row*64 + (((cj+1) ^ r) << 2));
        short8 a;
        a[0]=(short)f2bf(v0.x); a[1]=(short)f2bf(v0.y);
        a[2]=(short)f2bf(v0.z); a[3]=(short)f2bf(v0.w);
        a[4]=(short)f2bf(v1.x); a[5]=(short)f2bf(v1.y);
        a[6]=(short)f2bf(v1.z); a[7]=(short)f2bf(v1.w);
        af[h] = a;
    }

    // stage tasks: thread handles granule-tasks tid and tid+1024.
    // task t2: entry c=t2>>3 (0..255), granule j=t2&7; LDS slot j^(c&7).
    const int c0 = tid >> 3,        j0 = tid & 7;
    const int c1 = (tid + 1024) >> 3, j1 = tid & 7;     // c1 = c0 + 128
    const int d0 = (c0 << 6) + ((j0 ^ (c0 & 7)) << 3);  // ushort offsets in buffer
    const int d1 = (c1 << 6) + ((j1 ^ (c1 & 7)) << 3);

    __syncthreads();

    // ---- PASS 1: per-lane running max only (double-buffered staging) ----
    float rm[4];
    #pragma unroll
    for (int s = 0; s < 4; ++s) rm[s] = -3.402823466e38f;

    {
        short8 st0 = *(const short8*)(cbh + ((0 + c0) << 6) + (j0 << 3));
        short8 st1 = *(const short8*)(cbh + ((0 + c1) << 6) + (j1 << 3));
        *(short8*)(bsh + d0) = st0;
        *(short8*)(bsh + d1) = st1;
        __syncthreads();

        #pragma unroll 1
        for (int i = 0; i < NCH; ++i) {
            const int nb = i * BCH;
            const int cur = i & 1;
            if (i < NCH - 1) {
                st0 = *(const short8*)(cbh + ((nb + BCH + c0) << 6) + (j0 << 3));
                st1 = *(const short8*)(cbh + ((nb + BCH + c1) << 6) + (j1 << 3));
            }
            const unsigned short* bb = bsh + cur * BUF_USH;
            #pragma unroll
            for (int nt = 0; nt < 16; ++nt) {
                const float ch = -0.5f * csq_s[nb + nt*16 + r];
                f32x4 c; c[0]=ch; c[1]=ch; c[2]=ch; c[3]=ch;
                const unsigned short* bp = bb + ((nt*16 + r) << 6);
                short8 b0 = *(const short8*)(bp + (((g    ) ^ (r & 7)) << 3));  // h=0
                short8 b1 = *(const short8*)(bp + (((4 + g) ^ (r & 7)) << 3));  // h=1
                c = __builtin_amdgcn_mfma_f32_16x16x32_bf16(af[0], b0, c, 0, 0, 0);
                c = __builtin_amdgcn_mfma_f32_16x16x32_bf16(af[1], b1, c, 0, 0, 0);
                rm[0] = fmaxf(rm[0], c[0]);
                rm[1] = fmaxf(rm[1], c[1]);
                rm[2] = fmaxf(rm[2], c[2]);
                rm[3] = fmaxf(rm[3], c[3]);
            }
            if (i < NCH - 1) {
                unsigned short* wb = bsh + (cur ^ 1) * BUF_USH;
                *(short8*)(wb + d0) = st0;
                *(short8*)(wb + d1) = st1;
            }
            __syncthreads();
        }
    }

    // ---- one cross-lane reduce (over r bits) -> final per-row threshold ----
    float thr[4];
    #pragma unroll
    for (int s = 0; s < 4; ++s) {
        float cm = rm[s];
        cm = fmaxf(cm, __shfl_xor(cm, 1));
        cm = fmaxf(cm, __shfl_xor(cm, 2));
        cm = fmaxf(cm, __shfl_xor(cm, 4));
        cm = fmaxf(cm, __shfl_xor(cm, 8));
        thr[s] = cm - Ttab[wrow + g*4 + s];
    }

    // ---- PASS 2: recompute (bit-identical) + ballot-compacted flagging ----
    {
        short8 st0 = *(const short8*)(cbh + ((0 + c0) << 6) + (j0 << 3));
        short8 st1 = *(const short8*)(cbh + ((0 + c1) << 6) + (j1 << 3));
        *(short8*)(bsh + d0) = st0;
        *(short8*)(bsh + d1) = st1;
        __syncthreads();

        #pragma unroll 1
        for (int i = 0; i < NCH; ++i) {
            const int nb = i * BCH;
            const int cur = i & 1;
            if (i < NCH - 1) {
                st0 = *(const short8*)(cbh + ((nb + BCH + c0) << 6) + (j0 << 3));
                st1 = *(const short8*)(cbh + ((nb + BCH + c1) << 6) + (j1 << 3));
            }
            const unsigned short* bb = bsh + cur * BUF_USH;
            #pragma unroll 1
            for (int nt = 0; nt < 16; ++nt) {
                const float ch = -0.5f * csq_s[nb + nt*16 + r];
                f32x4 c; c[0]=ch; c[1]=ch; c[2]=ch; c[3]=ch;
                const unsigned short* bp = bb + ((nt*16 + r) << 6);
                short8 b0 = *(const short8*)(bp + (((g    ) ^ (r & 7)) << 3));
                short8 b1 = *(const short8*)(bp + (((4 + g) ^ (r & 7)) << 3));
                c = __builtin_amdgcn_mfma_f32_16x16x32_bf16(af[0], b0, c, 0, 0, 0);
                c = __builtin_amdgcn_mfma_f32_16x16x32_bf16(af[1], b1, c, 0, 0, 0);
                const bool f0 = c[0] >= thr[0];
                const bool f1 = c[1] >= thr[1];
                const bool f2 = c[2] >= thr[2];
                const bool f3 = c[3] >= thr[3];
                if (__ballot(f0 | f1 | f2 | f3)) {
                    const int ent = nb + nt*16 + r;
                    #pragma unroll
                    for (int rg = 0; rg < 4; ++rg) {
                        const bool fl = (rg==0)?f0:(rg==1)?f1:(rg==2)?f2:f3;
                        unsigned long long m = __ballot(fl);
                        if (m) {
                            int base = 0;
                            if (lane == 0) base = atomicAdd(&qcnt[w], (int)__popcll(m));
                            base = __builtin_amdgcn_readfirstlane(base);
                            if (fl) {
                                int pos = base + (int)__popcll(m & ((1ull << lane) - 1ull));
                                if (pos < QCAP)
                                    qbuf[w * QCAP + pos] =
                                        (unsigned short)(((g*4 + rg) << 10) | ent);
                                else *ovflp = 1;
                            }
                        }
                    }
                }
            }
            if (i < NCH - 1) {
                unsigned short* wb = bsh + (cur ^ 1) * BUF_USH;
                *(short8*)(wb + d0) = st0;
                *(short8*)(wb + d1) = st1;
            }
            __syncthreads();
        }
    }

    // ---- batched exact rescore (x from LDS, bit-identical) + atomicMin merge ----
    const int cnt  = qcnt[w];
    const int cmax = cnt < QCAP ? cnt : QCAP;
    for (int base = 0; base < cmax; base += 64) {
        const int i = base + lane;
        if (i < cmax) {
            const int item = qbuf[w * QCAP + i];
            const int row = wrow + (item >> 10);
            const int n = item & 1023;
            const float* xr = xs + row * 64;
            const int sr = row & 15;
            const float4* e4 = (const float4*)(cb + ((size_t)n << 6));
            float mm = 0.f;
            #pragma unroll
            for (int j = 0; j < 16; ++j) {
                float4 xq = *(const float4*)(xr + ((j ^ sr) << 2));
                float4 eq = e4[j];
                mm = __builtin_fmaf(xq.x, eq.x, mm);
                mm = __builtin_fmaf(xq.y, eq.y, mm);
                mm = __builtin_fmaf(xq.z, eq.z, mm);
                mm = __builtin_fmaf(xq.w, eq.w, mm);
            }
            float dd;
            {
                #pragma clang fp contract(off)
                dd = (Atab[row] - 2.0f * mm) + csq_s[n];
            }
            unsigned long long key =
                ((unsigned long long)__float_as_uint(dd) << 32) | (unsigned)n;
            atomicMin(&keytab[row], key);
        }
    }
    __syncthreads();

    // ---- per-row result, overflow fallback, code publish ----
    float* dtab = Ttab;                                // Ttab dead past thr computation
    if (tid < RPB) {
        unsigned long long kk = keytab[tid];
        int   kb = (int)(kk & 1023u);
        float db = __uint_as_float((unsigned)(kk >> 32));
        if (*ovflp) {   // practically unreachable; exact full scan
            const float* xr = in + (rowBase + tid) * (size_t)DIM;
            float dmin = 3.402823466e38f; int kmin = 0;
            for (int n = 0; n < KCB; ++n) {
                const float* eg = cb + ((size_t)n << 6);
                float mmv = 0.f;
                for (int j = 0; j < 64; ++j) mmv = __builtin_fmaf(xr[j], eg[j], mmv);
                float ddv;
                {
                    #pragma clang fp contract(off)
                    ddv = (Atab[tid] - 2.0f * mmv) + csq_s[n];
                }
                if (ddv < dmin) { dmin = ddv; kmin = n; }
            }
            db = dmin; kb = kmin;
        }
        dtab[tid] = db;
        codes_f[rowBase + tid] = (float)kb;
        keytab[tid] = (unsigned long long)(unsigned)kb;   // publish code for ST pass
    }
    __syncthreads();

    // ---- fused straight-through write: st = x + (q - x), x from LDS ----
    {
        float4* gout = (float4*)(out + rowBase * DIM);
        #pragma unroll
        for (int i = 0; i < 4; ++i) {
            int idx = i * 1024 + tid;
            int row = idx >> 4, cj = idx & 15;
            int code = (int)keytab[row];
            float4 qv = *(const float4*)(cb + ((size_t)code << 6) + (cj << 2));
            float4 xv = *(const float4*)(xs + row * 64 + ((cj ^ (row & 15)) << 2));
            float4 st;
            {
                #pragma clang fp contract(off)
                st.x = xv.x + (qv.x - xv.x);
                st.y = xv.y + (qv.y - xv.y);
                st.z = xv.z + (qv.z - xv.z);
                st.w = xv.w + (qv.w - xv.w);
            }
            gout[idx] = st;
        }
    }

    // ---- loss partial (identical 256-leaf tree) ----
    __syncthreads();
    #pragma unroll
    for (int s = 128; s > 0; s >>= 1) {
        if (tid < s) dtab[tid] += dtab[tid + s];
        __syncthreads();
    }
    if (tid == 0) atomicAdd(loss_acc, dtab[0]);
}

// ===================== fallback: R1 scalar kernel (used only if ws too small) ==========
#define OLD_SMEM_WORDS 20480
#define OLD_SMEM_BYTES (OLD_SMEM_WORDS * 4)

__global__ __launch_bounds__(512, 4) void vq_main_old(
        const float* __restrict__ in,
        const float* __restrict__ cb,
        const float* __restrict__ csq,
        float* __restrict__ codes_f,
        float* __restrict__ out,
        float* __restrict__ loss_acc)
{
    extern __shared__ float smem[];
    float* xs    = smem;
    float* dtab  = smem + 16384;
    int*   ktab  = (int*)(smem + 18432);

    const int tid  = threadIdx.x;
    const int lane = tid & 63;
    const int q    = __builtin_amdgcn_readfirstlane(tid >> 6);
    const size_t rowBase = (size_t)blockIdx.x * RPB;

    {
        const float4* gx = (const float4*)(in + rowBase * DIM);
        #pragma unroll
        for (int i = 0; i < 8; ++i) {
            int idx = i * 512 + tid;
            int row = idx >> 4, cj = idx & 15;
            float4 v = gx[idx];
            *(float4*)(xs + row * 64 + ((cj ^ (row & 15)) << 2)) = v;
        }
    }
    __syncthreads();

    float A[4];
    #pragma unroll
    for (int ri = 0; ri < 4; ++ri) {
        const int row = lane + (ri << 6);
        float xv[64];
        #pragma unroll
        for (int cj = 0; cj < 16; ++cj) {
            float4 v = *(const float4*)(xs + row * 64 + ((cj ^ (lane & 15)) << 2));
            xv[cj*4+0]=v.x; xv[cj*4+1]=v.y; xv[cj*4+2]=v.z; xv[cj*4+3]=v.w;
        }
        {
            #pragma clang fp contract(off)
            float racc[8];
            #pragma unroll
            for (int j = 0; j < 8; ++j) racc[j] = xv[j] * xv[j];
            #pragma unroll
            for (int t = 1; t < 8; ++t) {
                #pragma unroll
                for (int j = 0; j < 8; ++j) racc[j] += xv[8*t+j] * xv[8*t+j];
            }
            A[ri] = ((racc[0] + racc[1]) + (racc[2] + racc[3]))
                  + ((racc[4] + racc[5]) + (racc[6] + racc[7]));
        }
    }

    const float* cbq   = cb  + ((size_t)q << 13);
    const float* csq_q = csq + (q << 7);
    float dmin[4] = {3.402823466e38f, 3.402823466e38f, 3.402823466e38f, 3.402823466e38f};
    int   kmin[4] = {0, 0, 0, 0};
    const int xb = lane * 64;

    #pragma unroll 1
    for (int ke = 0; ke < 128; ke += 16) {
        float m[4][16];
        #pragma unroll
        for (int ri = 0; ri < 4; ++ri)
            #pragma unroll
            for (int e = 0; e < 16; ++e) m[ri][e] = 0.0f;

        #pragma unroll 1
        for (int jb = 0; jb < 64; jb += 4) {
            const int slot4 = ((jb >> 2) ^ (lane & 15)) << 2;
            float4 a0 = *(const float4*)(xs + xb +         slot4);
            float4 a1 = *(const float4*)(xs + xb +  4096 + slot4);
            float4 a2 = *(const float4*)(xs + xb +  8192 + slot4);
            float4 a3 = *(const float4*)(xs + xb + 12288 + slot4);
            #pragma unroll
            for (int e = 0; e < 16; ++e) {
                float4 ev = *(const float4*)(cbq + ((ke + e) << 6) + jb);
                m[0][e] = __builtin_fmaf(a0.x, ev.x, m[0][e]);
                m[0][e] = __builtin_fmaf(a0.y, ev.y, m[0][e]);
                m[0][e] = __builtin_fmaf(a0.z, ev.z, m[0][e]);
                m[0][e] = __builtin_fmaf(a0.w, ev.w, m[0][e]);
                m[1][e] = __builtin_fmaf(a1.x, ev.x, m[1][e]);
                m[1][e] = __builtin_fmaf(a1.y, ev.y, m[1][e]);
                m[1][e] = __builtin_fmaf(a1.z, ev.z, m[1][e]);
                m[1][e] = __builtin_fmaf(a1.w, ev.w, m[1][e]);
                m[2][e] = __builtin_fmaf(a2.x, ev.x, m[2][e]);
                m[2][e] = __builtin_fmaf(a2.y, ev.y, m[2][e]);
                m[2][e] = __builtin_fmaf(a2.z, ev.z, m[2][e]);
                m[2][e] = __builtin_fmaf(a2.w, ev.w, m[2][e]);
                m[3][e] = __builtin_fmaf(a3.x, ev.x, m[3][e]);
                m[3][e] = __builtin_fmaf(a3.y, ev.y, m[3][e]);
                m[3][e] = __builtin_fmaf(a3.z, ev.z, m[3][e]);
                m[3][e] = __builtin_fmaf(a3.w, ev.w, m[3][e]);
            }
        }

        #pragma unroll
        for (int e = 0; e < 16; ++e) {
            float cse = csq_q[ke + e];
            int gk = (q << 7) + ke + e;
            #pragma unroll
            for (int ri = 0; ri < 4; ++ri) {
                float d;
                {
                    #pragma clang fp contract(off)
                    d = (A[ri] - 2.0f * m[ri][e]) + cse;
                }
                if (d < dmin[ri]) { dmin[ri] = d; kmin[ri] = gk; }
            }
        }
    }

    #pragma unroll
    for (int ri = 0; ri < 4; ++ri) {
        int row = lane + (ri << 6);
        dtab[row * 8 + q] = dmin[ri];
        ktab[row * 8 + q] = kmin[ri];
    }
    __syncthreads();

    float db = 0.0f;
    if (tid < RPB) {
        db = dtab[tid * 8];
        int kb = ktab[tid * 8];
        #pragma unroll
        for (int qq = 1; qq < 8; ++qq) {
            float dq = dtab[tid * 8 + qq];
            int   kq = ktab[tid * 8 + qq];
            if (dq < db) { db = dq; kb = kq; }
        }
        ktab[tid * 8] = kb;
        codes_f[rowBase + tid] = (float)kb;
    }
    __syncthreads();

    {
        float4* gout = (float4*)(out + rowBase * DIM);
        #pragma unroll
        for (int i = 0; i < 8; ++i) {
            int idx = i * 512 + tid;
            int row = idx >> 4, cj = idx & 15;
            int code = ktab[row * 8];
            float4 qv = *(const float4*)(cb + ((size_t)code << 6) + (cj << 2));
            float4 xv = *(const float4*)(xs + row * 64 + ((cj ^ (row & 15)) << 2));
            float4 st;
            {
                #pragma clang fp contract(off)
                st.x = xv.x + (qv.x - xv.x);
                st.y = xv.y + (qv.y - xv.y);
                st.z = xv.z + (qv.z - xv.z);
                st.w = xv.w + (qv.w - xv.w);
            }
            gout[idx] = st;
        }
    }

    if (tid < RPB) dtab[tid] = db;
    __syncthreads();
    #pragma unroll
    for (int s = 128; s > 0; s >>= 1) {
        if (tid < s) dtab[tid] += dtab[tid + s];
        __syncthreads();
    }
    if (tid == 0) atomicAdd(loss_acc, dtab[0]);
}

__global__ void vq_final(const float* __restrict__ ws, float* __restrict__ loss_out) {
    loss_out[0] = 1.25f * ws[0] / 8388608.0f;
}

extern "C" void kernel_launch(void* const* d_in, const int* in_sizes, int n_in,
                              void* d_out, int out_size, void* d_ws, size_t ws_size,
                              hipStream_t stream) {
    const float* in = (const float*)d_in[0];   // (32,4096,64) fp32
    const float* cb = (const float*)d_in[1];   // (1024,64)    fp32
    float* out     = (float*)d_out;
    float* codes_f = out + 8388608;
    float* loss_p  = out + 8519680;
    float* ws      = (float*)d_ws;

    const int big = (ws_size >= (size_t)WS_NEED_BYTES) ? 1 : 0;

    vq_prep<<<16, 64, 0, stream>>>(cb, ws, big);
    if (big) {
        hipFuncSetAttribute((const void*)vq_mfma,
                            hipFuncAttributeMaxDynamicSharedMemorySize, SMEM_BYTES);
        vq_mfma<<<512, 1024, SMEM_BYTES, stream>>>(in, cb, ws, codes_f, out);
    } else {
        hipFuncSetAttribute((const void*)vq_main_old,
                            hipFuncAttributeMaxDynamicSharedMemorySize, OLD_SMEM_BYTES);
        vq_main_old<<<512, 512, OLD_SMEM_BYTES, stream>>>(in, cb, ws + 256, codes_f, out, ws);
    }
    vq_final<<<1, 1, 0, stream>>>(ws, loss_p);
}

// Round 11
// 152.097 us; speedup vs baseline: 1.0615x; 1.0615x over previous
//
#include <hip/hip_runtime.h>

#define DIM   64
#define KCB   1024
#define RPB   256
#define QCAP  192      // per-wave queue (32 rows x half-codebook), u16 items
#define BCH   256      // entries per staged chunk: 128 (half 0) + 128 (half 1)
#define NCH   4        // chunks per pass

// dynamic LDS layout (float words):
//  xs     [16384]               swizzled x (word = row*64 + ((cj^(row&15))<<2))
//  Atab   [256]  @16384
//  Ttab   [256]  @16640         (reused as dtab for the loss tree)
//  csq_s  [1024] @16896
//  keytab [256 u64] @17920 (512 words)
//  qcnt   [16 int] @18432
//  ovfl   @18448
//  qbuf   u16[16][QCAP] @18449  (1536 words) -> ends 19985
//  rmtab  [256][2] @19988 (512 words) -> ends 20500
//  bsh    @20500 (byte 82000, 16B-aligned): TWO buffers, each BCH entries x
//         32 words; 16B-granule j of entry-slot c at slot j^(c&7).
#define RMT_OFS 19988
#define BSH_OFS 20500
#define BUF_USH (BCH * 64)                  // ushorts per buffer (16384)
#define SMEM_WORDS (BSH_OFS + 2 * BCH * 32) // 36884 words = 147,536 B -> 1 block/CU
#define SMEM_BYTES (SMEM_WORDS * 4)

// ws layout (floats): ws[0] = loss acc; ws[256..1279] = csq[k];
//                     ws[2048..] = cb_hi bf16 [1024][64] (32768 float slots)
#define WS_NEED_BYTES ((2048 + 32768) * 4)

typedef __attribute__((ext_vector_type(8))) short short8;
typedef __attribute__((ext_vector_type(4))) float f32x4;

__device__ __forceinline__ unsigned short f2bf(float f) {
    union { float f; unsigned u; } v; v.f = f;
    unsigned u = v.u;
    return (unsigned short)((u + 0x7FFFu + ((u >> 16) & 1u)) >> 16);  // RNE
}

// async global->LDS 16B: per-lane LINEAR dest (base + lane*16), per-lane src.
__device__ __forceinline__ void gload_lds16(const unsigned short* g, unsigned short* l) {
    __builtin_amdgcn_global_load_lds(
        (const __attribute__((address_space(1))) unsigned int*)g,
        (__attribute__((address_space(3))) unsigned int*)l, 16, 0, 0);
}

__global__ void vq_prep(const float* __restrict__ cb, float* __restrict__ ws, int do_bf) {
    int k = blockIdx.x * blockDim.x + threadIdx.x;
    if (k < KCB) {
        const float4* e4 = (const float4*)(cb + (k << 6));
        float4 xq[16];
        #pragma unroll
        for (int j = 0; j < 16; ++j) xq[j] = e4[j];
        {
            #pragma clang fp contract(off)
            float racc[8];
            racc[0]=xq[0].x*xq[0].x; racc[1]=xq[0].y*xq[0].y;
            racc[2]=xq[0].z*xq[0].z; racc[3]=xq[0].w*xq[0].w;
            racc[4]=xq[1].x*xq[1].x; racc[5]=xq[1].y*xq[1].y;
            racc[6]=xq[1].z*xq[1].z; racc[7]=xq[1].w*xq[1].w;
            #pragma unroll
            for (int t = 1; t < 8; ++t) {
                float4 a = xq[2*t], b = xq[2*t+1];
                racc[0]+=a.x*a.x; racc[1]+=a.y*a.y; racc[2]+=a.z*a.z; racc[3]+=a.w*a.w;
                racc[4]+=b.x*b.x; racc[5]+=b.y*b.y; racc[6]+=b.z*b.z; racc[7]+=b.w*b.w;
            }
            ws[256 + k] = ((racc[0] + racc[1]) + (racc[2] + racc[3]))
                        + ((racc[4] + racc[5]) + (racc[6] + racc[7]));
        }
        if (do_bf) {
            short8* dst = (short8*)((unsigned short*)(ws + 2048) + (k << 6));
            #pragma unroll
            for (int p = 0; p < 8; ++p) {
                float4 v = xq[2*p], u = xq[2*p+1];
                short8 s;
                s[0]=(short)f2bf(v.x); s[1]=(short)f2bf(v.y);
                s[2]=(short)f2bf(v.z); s[3]=(short)f2bf(v.w);
                s[4]=(short)f2bf(u.x); s[5]=(short)f2bf(u.y);
                s[6]=(short)f2bf(u.z); s[7]=(short)f2bf(u.w);
                dst[p] = s;
            }
        }
    }
    if (k == 0) ws[0] = 0.0f;
}

// Two-pass MFMA-filtered VQ — entry-half split + async LDS staging:
//  - R9/R10 wall: 16 waves x full codebook = 4 MB/block of ds_read_b128 (~50%
//    of block cycles). R11: wave w = row-group (w&7, 32 rows, mt=2) x entry
//    half (w>>3, 512 entries). Each b0/b1 read feeds 2 MFMAs; B ds_reads 2x
//    down. Cross-half threshold combine via rmtab (fmax exact -> same thr ->
//    same flag set -> bit-identical outputs).
//  - staging via global_load_lds width 16, linear dest + pre-swizzled source
//    (granule s^(c&7)) -> no staging registers, no spill; double-buffered,
//    loads in flight across the chunk's compute, drained by the end barrier.
__global__ __launch_bounds__(1024, 1) void vq_mfma(
        const float* __restrict__ in,
        const float* __restrict__ cb,
        float* __restrict__ ws,
        float* __restrict__ codes_f,
        float* __restrict__ out)
{
    extern __shared__ float smem[];
    float* xs    = smem;
    float* Atab  = smem + 16384;
    float* Ttab  = smem + 16640;                       // reused as dtab
    float* csq_s = smem + 16896;
    unsigned long long* keytab = (unsigned long long*)(smem + 17920);
    int* qcnt  = (int*)(smem + 18432);                 // [16]
    int* ovflp = (int*)(smem + 18448);
    unsigned short* qbuf = (unsigned short*)(smem + 18449);  // [16][QCAP]
    float* rmtab = smem + RMT_OFS;                     // [256][2]
    unsigned short* bsh = (unsigned short*)(smem + BSH_OFS); // 2 x BUF_USH

    const int tid  = threadIdx.x;
    const int lane = tid & 63;
    const int w    = tid >> 6;                         // wave 0..15
    const int r    = lane & 15;
    const int g    = lane >> 4;
    const int half = w >> 3;                           // entry half 0/1
    const int wrow2 = (w & 7) << 5;                    // 32 rows per row-group
    const size_t rowBase = (size_t)blockIdx.x * RPB;
    const float* csq = ws + 256;
    const unsigned short* cbh = (const unsigned short*)(ws + 2048);
    float* loss_acc = ws;

    // ---- stage x once (swizzled), csq, init tabs ----
    {
        const float4* gx = (const float4*)(in + rowBase * DIM);
        #pragma unroll
        for (int i = 0; i < 4; ++i) {
            int idx = i * 1024 + tid;
            int row = idx >> 4, cj = idx & 15;
            float4 v = gx[idx];
            *(float4*)(xs + row * 64 + ((cj ^ (row & 15)) << 2)) = v;
        }
    }
    csq_s[tid] = csq[tid];                             // 1024 threads cover KCB
    if (tid < RPB) keytab[tid] = 0xFFFFFFFFFFFFFFFFull;
    if (tid < 16) qcnt[tid] = 0;
    if (tid == 0) *ovflp = 0;
    __syncthreads();

    // ---- per-row A (exact pairwise-8 order), S1, tau (row = tid; from LDS) ----
    if (tid < RPB) {
        const float* xr = xs + tid * 64;
        const int s = tid & 15;
        float A, S1;
        {
            #pragma clang fp contract(off)
            float racc[8], sacc[8];
            {
                float4 a = *(const float4*)(xr + ((0 ^ s) << 2));
                float4 b = *(const float4*)(xr + ((1 ^ s) << 2));
                racc[0]=a.x*a.x; racc[1]=a.y*a.y; racc[2]=a.z*a.z; racc[3]=a.w*a.w;
                racc[4]=b.x*b.x; racc[5]=b.y*b.y; racc[6]=b.z*b.z; racc[7]=b.w*b.w;
                sacc[0]=__builtin_fabsf(a.x); sacc[1]=__builtin_fabsf(a.y);
                sacc[2]=__builtin_fabsf(a.z); sacc[3]=__builtin_fabsf(a.w);
                sacc[4]=__builtin_fabsf(b.x); sacc[5]=__builtin_fabsf(b.y);
                sacc[6]=__builtin_fabsf(b.z); sacc[7]=__builtin_fabsf(b.w);
            }
            #pragma unroll
            for (int t = 1; t < 8; ++t) {
                float4 a = *(const float4*)(xr + (((2*t)   ^ s) << 2));
                float4 b = *(const float4*)(xr + (((2*t+1) ^ s) << 2));
                racc[0]+=a.x*a.x; racc[1]+=a.y*a.y; racc[2]+=a.z*a.z; racc[3]+=a.w*a.w;
                racc[4]+=b.x*b.x; racc[5]+=b.y*b.y; racc[6]+=b.z*b.z; racc[7]+=b.w*b.w;
                sacc[0]+=__builtin_fabsf(a.x); sacc[1]+=__builtin_fabsf(a.y);
                sacc[2]+=__builtin_fabsf(a.z); sacc[3]+=__builtin_fabsf(a.w);
                sacc[4]+=__builtin_fabsf(b.x); sacc[5]+=__builtin_fabsf(b.y);
                sacc[6]+=__builtin_fabsf(b.z); sacc[7]+=__builtin_fabsf(b.w);
            }
            A  = ((racc[0]+racc[1])+(racc[2]+racc[3]))
               + ((racc[4]+racc[5])+(racc[6]+racc[7]));
            S1 = ((sacc[0]+sacc[1])+(sacc[2]+sacc[3]))
               + ((sacc[4]+sacc[5])+(sacc[6]+sacc[7]));
        }
        Atab[tid] = A;
        Ttab[tid] = 1.52587890625e-05f * S1
                  + 4.76837158203125e-07f * (A + 1.0f)
                  + 1e-5f;                             // certified >= 2E (R2-R10 verified)
    }

    // ---- A-fragments (bf16 hi of x) from LDS (rows wrow2 + mt*16 + r) ----
    short8 af[2][2];
    #pragma unroll
    for (int mt = 0; mt < 2; ++mt)
        #pragma unroll
        for (int h = 0; h < 2; ++h) {
            const int row = wrow2 + mt*16 + r;         // row&15 == r
            const int cj = h*8 + g*2;
            float4 v0 = *(const float4*)(xs + row*64 + (((cj  ) ^ r) << 2));
            float4 v1 = *(const float4*)(xs + row*64 + (((cj+1) ^ r) << 2));
            short8 a;
            a[0]=(short)f2bf(v0.x); a[1]=(short)f2bf(v0.y);
            a[2]=(short)f2bf(v0.z); a[3]=(short)f2bf(v0.w);
            a[4]=(short)f2bf(v1.x); a[5]=(short)f2bf(v1.y);
            a[6]=(short)f2bf(v1.z); a[7]=(short)f2bf(v1.w);
            af[mt][h] = a;
        }

    // staging task: thread t fills linear 16B-slots t and t+1024 of a buffer.
    // slot L: entry-slot c=L>>3, sub-slot s=L&7 holds granule s^(c&7).
    // entry-slot c<128 -> global entry i*128+c (half 0); c>=128 -> +512-128.
    const int c0  = tid >> 3;                          // 0..127
    const int gr0 = (tid & 7) ^ (c0 & 7);              // source granule
    #define STAGE_CHUNK(i_, buf_) do {                                          \
        const unsigned short* _s = cbh + ((((i_) << 7) + c0) << 6) + (gr0 << 3);\
        unsigned short* _d = bsh + (buf_) * BUF_USH + (tid << 3);               \
        gload_lds16(_s, _d);                                                    \
        gload_lds16(_s + (512 << 6), _d + 8192);                                \
    } while (0)

    // ---- PASS 1: per-lane running max only ----
    float rm[8];
    #pragma unroll
    for (int s = 0; s < 8; ++s) rm[s] = -3.402823466e38f;

    STAGE_CHUNK(0, 0);
    __syncthreads();                                   // drains chunk 0
    #pragma unroll 1
    for (int i = 0; i < NCH; ++i) {
        if (i < NCH - 1) STAGE_CHUNK(i + 1, (i & 1) ^ 1);
        const unsigned short* bb = bsh + (i & 1) * BUF_USH;
        const int nb128 = i << 7;
        #pragma unroll
        for (int nt = 0; nt < 8; ++nt) {
            const int ent = (half << 9) + nb128 + nt*16 + r;
            const float ch = -0.5f * csq_s[ent];
            f32x4 a0, a1;
            a0[0]=ch; a0[1]=ch; a0[2]=ch; a0[3]=ch;
            a1[0]=ch; a1[1]=ch; a1[2]=ch; a1[3]=ch;
            const unsigned short* bp = bb + (((half << 7) + nt*16 + r) << 6);
            short8 b0 = *(const short8*)(bp + (((g    ) ^ (r & 7)) << 3));  // h=0
            short8 b1 = *(const short8*)(bp + (((4 + g) ^ (r & 7)) << 3));  // h=1
            a0 = __builtin_amdgcn_mfma_f32_16x16x32_bf16(af[0][0], b0, a0, 0, 0, 0);
            a0 = __builtin_amdgcn_mfma_f32_16x16x32_bf16(af[0][1], b1, a0, 0, 0, 0);
            a1 = __builtin_amdgcn_mfma_f32_16x16x32_bf16(af[1][0], b0, a1, 0, 0, 0);
            a1 = __builtin_amdgcn_mfma_f32_16x16x32_bf16(af[1][1], b1, a1, 0, 0, 0);
            rm[0]=fmaxf(rm[0],a0[0]); rm[1]=fmaxf(rm[1],a0[1]);
            rm[2]=fmaxf(rm[2],a0[2]); rm[3]=fmaxf(rm[3],a0[3]);
            rm[4]=fmaxf(rm[4],a1[0]); rm[5]=fmaxf(rm[5],a1[1]);
            rm[6]=fmaxf(rm[6],a1[2]); rm[7]=fmaxf(rm[7],a1[3]);
        }
        __syncthreads();                               // drains next chunk + turnover
    }

    // ---- per-row half-max -> rmtab; combine halves -> final threshold ----
    #pragma unroll
    for (int s = 0; s < 8; ++s) {
        float cm = rm[s];
        cm = fmaxf(cm, __shfl_xor(cm, 1));
        cm = fmaxf(cm, __shfl_xor(cm, 2));
        cm = fmaxf(cm, __shfl_xor(cm, 4));
        cm = fmaxf(cm, __shfl_xor(cm, 8));
        rm[s] = cm;
    }
    if (r == 0) {
        #pragma unroll
        for (int s = 0; s < 8; ++s) {
            const int row = wrow2 + (s >> 2)*16 + g*4 + (s & 3);
            rmtab[row * 2 + half] = rm[s];
        }
    }
    STAGE_CHUNK(0, 0);                                 // pass-2 chunk 0 prefetch
    __syncthreads();                                   // publishes rmtab + drains
    float thr[8];
    #pragma unroll
    for (int s = 0; s < 8; ++s) {
        const int row = wrow2 + (s >> 2)*16 + g*4 + (s & 3);
        thr[s] = fmaxf(rmtab[row * 2], rmtab[row * 2 + 1]) - Ttab[row];
    }

    // ---- PASS 2: recompute (bit-identical) + ballot-compacted flagging ----
    #pragma unroll 1
    for (int i = 0; i < NCH; ++i) {
        if (i < NCH - 1) STAGE_CHUNK(i + 1, (i & 1) ^ 1);
        const unsigned short* bb = bsh + (i & 1) * BUF_USH;
        const int nb128 = i << 7;
        #pragma unroll 1
        for (int nt = 0; nt < 8; ++nt) {
            const int ent = (half << 9) + nb128 + nt*16 + r;
            const float ch = -0.5f * csq_s[ent];
            f32x4 a0, a1;
            a0[0]=ch; a0[1]=ch; a0[2]=ch; a0[3]=ch;
            a1[0]=ch; a1[1]=ch; a1[2]=ch; a1[3]=ch;
            const unsigned short* bp = bb + (((half << 7) + nt*16 + r) << 6);
            short8 b0 = *(const short8*)(bp + (((g    ) ^ (r & 7)) << 3));
            short8 b1 = *(const short8*)(bp + (((4 + g) ^ (r & 7)) << 3));
            a0 = __builtin_amdgcn_mfma_f32_16x16x32_bf16(af[0][0], b0, a0, 0, 0, 0);
            a0 = __builtin_amdgcn_mfma_f32_16x16x32_bf16(af[0][1], b1, a0, 0, 0, 0);
            a1 = __builtin_amdgcn_mfma_f32_16x16x32_bf16(af[1][0], b0, a1, 0, 0, 0);
            a1 = __builtin_amdgcn_mfma_f32_16x16x32_bf16(af[1][1], b1, a1, 0, 0, 0);
            bool fl[8];
            fl[0]=a0[0]>=thr[0]; fl[1]=a0[1]>=thr[1];
            fl[2]=a0[2]>=thr[2]; fl[3]=a0[3]>=thr[3];
            fl[4]=a1[0]>=thr[4]; fl[5]=a1[1]>=thr[5];
            fl[6]=a1[2]>=thr[6]; fl[7]=a1[3]>=thr[7];
            bool any = fl[0]|fl[1]|fl[2]|fl[3]|fl[4]|fl[5]|fl[6]|fl[7];
            if (__ballot(any)) {                       // uniform coarse skip
                #pragma unroll
                for (int s = 0; s < 8; ++s) {
                    unsigned long long m = __ballot(fl[s]);
                    if (m) {
                        int base = 0;
                        if (lane == 0) base = atomicAdd(&qcnt[w], (int)__popcll(m));
                        base = __builtin_amdgcn_readfirstlane(base);
                        if (fl[s]) {
                            const int rowLocal = (s >> 2)*16 + g*4 + (s & 3); // 0..31
                            int pos = base + (int)__popcll(m & ((1ull << lane) - 1ull));
                            if (pos < QCAP)
                                qbuf[w * QCAP + pos] =
                                    (unsigned short)((rowLocal << 10) | ent);
                            else *ovflp = 1;
                        }
                    }
                }
            }
        }
        __syncthreads();
    }

    // ---- batched exact rescore (x from LDS, bit-identical) + atomicMin merge ----
    const int cnt  = qcnt[w];
    const int cmax = cnt < QCAP ? cnt : QCAP;
    for (int base = 0; base < cmax; base += 64) {
        const int i = base + lane;
        if (i < cmax) {
            const int item = qbuf[w * QCAP + i];
            const int row = wrow2 + (item >> 10);
            const int n = item & 1023;
            const float* xr = xs + row * 64;
            const int sr = row & 15;
            const float4* e4 = (const float4*)(cb + ((size_t)n << 6));
            float mm = 0.f;
            #pragma unroll
            for (int j = 0; j < 16; ++j) {
                float4 xq = *(const float4*)(xr + ((j ^ sr) << 2));
                float4 eq = e4[j];
                mm = __builtin_fmaf(xq.x, eq.x, mm);
                mm = __builtin_fmaf(xq.y, eq.y, mm);
                mm = __builtin_fmaf(xq.z, eq.z, mm);
                mm = __builtin_fmaf(xq.w, eq.w, mm);
            }
            float dd;
            {
                #pragma clang fp contract(off)
                dd = (Atab[row] - 2.0f * mm) + csq_s[n];
            }
            unsigned long long key =
                ((unsigned long long)__float_as_uint(dd) << 32) | (unsigned)n;
            atomicMin(&keytab[row], key);
        }
    }
    __syncthreads();

    // ---- per-row result, overflow fallback, code publish ----
    float* dtab = Ttab;                                // Ttab dead past thr computation
    if (tid < RPB) {
        unsigned long long kk = keytab[tid];
        int   kb = (int)(kk & 1023u);
        float db = __uint_as_float((unsigned)(kk >> 32));
        if (*ovflp) {   // practically unreachable; exact full scan
            const float* xr = in + (rowBase + tid) * (size_t)DIM;
            float dmin = 3.402823466e38f; int kmin = 0;
            for (int n = 0; n < KCB; ++n) {
                const float* eg = cb + ((size_t)n << 6);
                float mmv = 0.f;
                for (int j = 0; j < 64; ++j) mmv = __builtin_fmaf(xr[j], eg[j], mmv);
                float ddv;
                {
                    #pragma clang fp contract(off)
                    ddv = (Atab[tid] - 2.0f * mmv) + csq_s[n];
                }
                if (ddv < dmin) { dmin = ddv; kmin = n; }
            }
            db = dmin; kb = kmin;
        }
        dtab[tid] = db;
        codes_f[rowBase + tid] = (float)kb;
        keytab[tid] = (unsigned long long)(unsigned)kb;   // publish code for ST pass
    }
    __syncthreads();

    // ---- fused straight-through write: st = x + (q - x), x from LDS ----
    {
        float4* gout = (float4*)(out + rowBase * DIM);
        #pragma unroll
        for (int i = 0; i < 4; ++i) {
            int idx = i * 1024 + tid;
            int row = idx >> 4, cj = idx & 15;
            int code = (int)keytab[row];
            float4 qv = *(const float4*)(cb + ((size_t)code << 6) + (cj << 2));
            float4 xv = *(const float4*)(xs + row * 64 + ((cj ^ (row & 15)) << 2));
            float4 st;
            {
                #pragma clang fp contract(off)
                st.x = xv.x + (qv.x - xv.x);
                st.y = xv.y + (qv.y - xv.y);
                st.z = xv.z + (qv.z - xv.z);
                st.w = xv.w + (qv.w - xv.w);
            }
            gout[idx] = st;
        }
    }

    // ---- loss partial (identical 256-leaf tree) ----
    __syncthreads();
    #pragma unroll
    for (int s = 128; s > 0; s >>= 1) {
        if (tid < s) dtab[tid] += dtab[tid + s];
        __syncthreads();
    }
    if (tid == 0) atomicAdd(loss_acc, dtab[0]);
}

// ===================== fallback: R1 scalar kernel (used only if ws too small) ==========
#define OLD_SMEM_WORDS 20480
#define OLD_SMEM_BYTES (OLD_SMEM_WORDS * 4)

__global__ __launch_bounds__(512, 4) void vq_main_old(
        const float* __restrict__ in,
        const float* __restrict__ cb,
        const float* __restrict__ csq,
        float* __restrict__ codes_f,
        float* __restrict__ out,
        float* __restrict__ loss_acc)
{
    extern __shared__ float smem[];
    float* xs    = smem;
    float* dtab  = smem + 16384;
    int*   ktab  = (int*)(smem + 18432);

    const int tid  = threadIdx.x;
    const int lane = tid & 63;
    const int q    = __builtin_amdgcn_readfirstlane(tid >> 6);
    const size_t rowBase = (size_t)blockIdx.x * RPB;

    {
        const float4* gx = (const float4*)(in + rowBase * DIM);
        #pragma unroll
        for (int i = 0; i < 8; ++i) {
            int idx = i * 512 + tid;
            int row = idx >> 4, cj = idx & 15;
            float4 v = gx[idx];
            *(float4*)(xs + row * 64 + ((cj ^ (row & 15)) << 2)) = v;
        }
    }
    __syncthreads();

    float A[4];
    #pragma unroll
    for (int ri = 0; ri < 4; ++ri) {
        const int row = lane + (ri << 6);
        float xv[64];
        #pragma unroll
        for (int cj = 0; cj < 16; ++cj) {
            float4 v = *(const float4*)(xs + row * 64 + ((cj ^ (lane & 15)) << 2));
            xv[cj*4+0]=v.x; xv[cj*4+1]=v.y; xv[cj*4+2]=v.z; xv[cj*4+3]=v.w;
        }
        {
            #pragma clang fp contract(off)
            float racc[8];
            #pragma unroll
            for (int j = 0; j < 8; ++j) racc[j] = xv[j] * xv[j];
            #pragma unroll
            for (int t = 1; t < 8; ++t) {
                #pragma unroll
                for (int j = 0; j < 8; ++j) racc[j] += xv[8*t+j] * xv[8*t+j];
            }
            A[ri] = ((racc[0] + racc[1]) + (racc[2] + racc[3]))
                  + ((racc[4] + racc[5]) + (racc[6] + racc[7]));
        }
    }

    const float* cbq   = cb  + ((size_t)q << 13);
    const float* csq_q = csq + (q << 7);
    float dmin[4] = {3.402823466e38f, 3.402823466e38f, 3.402823466e38f, 3.402823466e38f};
    int   kmin[4] = {0, 0, 0, 0};
    const int xb = lane * 64;

    #pragma unroll 1
    for (int ke = 0; ke < 128; ke += 16) {
        float m[4][16];
        #pragma unroll
        for (int ri = 0; ri < 4; ++ri)
            #pragma unroll
            for (int e = 0; e < 16; ++e) m[ri][e] = 0.0f;

        #pragma unroll 1
        for (int jb = 0; jb < 64; jb += 4) {
            const int slot4 = ((jb >> 2) ^ (lane & 15)) << 2;
            float4 a0 = *(const float4*)(xs + xb +         slot4);
            float4 a1 = *(const float4*)(xs + xb +  4096 + slot4);
            float4 a2 = *(const float4*)(xs + xb +  8192 + slot4);
            float4 a3 = *(const float4*)(xs + xb + 12288 + slot4);
            #pragma unroll
            for (int e = 0; e < 16; ++e) {
                float4 ev = *(const float4*)(cbq + ((ke + e) << 6) + jb);
                m[0][e] = __builtin_fmaf(a0.x, ev.x, m[0][e]);
                m[0][e] = __builtin_fmaf(a0.y, ev.y, m[0][e]);
                m[0][e] = __builtin_fmaf(a0.z, ev.z, m[0][e]);
                m[0][e] = __builtin_fmaf(a0.w, ev.w, m[0][e]);
                m[1][e] = __builtin_fmaf(a1.x, ev.x, m[1][e]);
                m[1][e] = __builtin_fmaf(a1.y, ev.y, m[1][e]);
                m[1][e] = __builtin_fmaf(a1.z, ev.z, m[1][e]);
                m[1][e] = __builtin_fmaf(a1.w, ev.w, m[1][e]);
                m[2][e] = __builtin_fmaf(a2.x, ev.x, m[2][e]);
                m[2][e] = __builtin_fmaf(a2.y, ev.y, m[2][e]);
                m[2][e] = __builtin_fmaf(a2.z, ev.z, m[2][e]);
                m[2][e] = __builtin_fmaf(a2.w, ev.w, m[2][e]);
                m[3][e] = __builtin_fmaf(a3.x, ev.x, m[3][e]);
                m[3][e] = __builtin_fmaf(a3.y, ev.y, m[3][e]);
                m[3][e] = __builtin_fmaf(a3.z, ev.z, m[3][e]);
                m[3][e] = __builtin_fmaf(a3.w, ev.w, m[3][e]);
            }
        }

        #pragma unroll
        for (int e = 0; e < 16; ++e) {
            float cse = csq_q[ke + e];
            int gk = (q << 7) + ke + e;
            #pragma unroll
            for (int ri = 0; ri < 4; ++ri) {
                float d;
                {
                    #pragma clang fp contract(off)
                    d = (A[ri] - 2.0f * m[ri][e]) + cse;
                }
                if (d < dmin[ri]) { dmin[ri] = d; kmin[ri] = gk; }
            }
        }
    }

    #pragma unroll
    for (int ri = 0; ri < 4; ++ri) {
        int row = lane + (ri << 6);
        dtab[row * 8 + q] = dmin[ri];
        ktab[row * 8 + q] = kmin[ri];
    }
    __syncthreads();

    float db = 0.0f;
    if (tid < RPB) {
        db = dtab[tid * 8];
        int kb = ktab[tid * 8];
        #pragma unroll
        for (int qq = 1; qq < 8; ++qq) {
            float dq = dtab[tid * 8 + qq];
            int   kq = ktab[tid * 8 + qq];
            if (dq < db) { db = dq; kb = kq; }
        }
        ktab[tid * 8] = kb;
        codes_f[rowBase + tid] = (float)kb;
    }
    __syncthreads();

    {
        float4* gout = (float4*)(out + rowBase * DIM);
        #pragma unroll
        for (int i = 0; i < 8; ++i) {
            int idx = i * 512 + tid;
            int row = idx >> 4, cj = idx & 15;
            int code = ktab[row * 8];
            float4 qv = *(const float4*)(cb + ((size_t)code << 6) + (cj << 2));
            float4 xv = *(const float4*)(xs + row * 64 + ((cj ^ (row & 15)) << 2));
            float4 st;
            {
                #pragma clang fp contract(off)
                st.x = xv.x + (qv.x - xv.x);
                st.y = xv.y + (qv.y - xv.y);
                st.z = xv.z + (qv.z - xv.z);
                st.w = xv.w + (qv.w - xv.w);
            }
            gout[idx] = st;
        }
    }

    if (tid < RPB) dtab[tid] = db;
    __syncthreads();
    #pragma unroll
    for (int s = 128; s > 0; s >>= 1) {
        if (tid < s) dtab[tid] += dtab[tid + s];
        __syncthreads();
    }
    if (tid == 0) atomicAdd(loss_acc, dtab[0]);
}

__global__ void vq_final(const float* __restrict__ ws, float* __restrict__ loss_out) {
    loss_out[0] = 1.25f * ws[0] / 8388608.0f;
}

extern "C" void kernel_launch(void* const* d_in, const int* in_sizes, int n_in,
                              void* d_out, int out_size, void* d_ws, size_t ws_size,
                              hipStream_t stream) {
    const float* in = (const float*)d_in[0];   // (32,4096,64) fp32
    const float* cb = (const float*)d_in[1];   // (1024,64)    fp32
    float* out     = (float*)d_out;
    float* codes_f = out + 8388608;
    float* loss_p  = out + 8519680;
    float* ws      = (float*)d_ws;

    const int big = (ws_size >= (size_t)WS_NEED_BYTES) ? 1 : 0;

    vq_prep<<<16, 64, 0, stream>>>(cb, ws, big);
    if (big) {
        hipFuncSetAttribute((const void*)vq_mfma,
                            hipFuncAttributeMaxDynamicSharedMemorySize, SMEM_BYTES);
        vq_mfma<<<512, 1024, SMEM_BYTES, stream>>>(in, cb, ws, codes_f, out);
    } else {
        hipFuncSetAttribute((const void*)vq_main_old,
                            hipFuncAttributeMaxDynamicSharedMemorySize, OLD_SMEM_BYTES);
        vq_main_old<<<512, 512, OLD_SMEM_BYTES, stream>>>(in, cb, ws + 256, codes_f, out, ws);
    }
    vq_final<<<1, 1, 0, stream>>>(ws, loss_p);
}